// Round 17
// baseline (277.611 us; speedup 1.0000x reference)
//
#include <hip/hip_runtime.h>

typedef unsigned short u16;
typedef unsigned int u32;
typedef __attribute__((ext_vector_type(8))) short short8;
typedef __attribute__((ext_vector_type(4))) float f32x4;
typedef __attribute__((ext_vector_type(4))) unsigned short u16x4;

extern "C" __device__ float __ocml_native_exp2_f32(float);
#define EXP2(x) __ocml_native_exp2_f32(x)

__device__ __forceinline__ float b2f(u16 u){
  union { float f; unsigned int i; } c; c.i = ((unsigned int)u) << 16; return c.f;
}
__device__ __forceinline__ u16 f2b(float f){
  union { float f; unsigned int i; } c; c.f = f;
  unsigned int i = c.i;
  unsigned int r = (i + 0x7FFFu + ((i >> 16) & 1u)) >> 16;
  return (u16)r;
}

#define GLD16(gp, lp) __builtin_amdgcn_global_load_lds( \
    (const __attribute__((address_space(1))) void*)(gp), \
    (__attribute__((address_space(3))) void*)(lp), 16, 0, 0)

__device__ __forceinline__ u32 pkbf(float lo, float hi){
  u32 r;
  asm volatile("v_cvt_pk_bf16_f32 %0, %1, %2" : "=v"(r) : "v"(lo), "v"(hi));
  return r;
}

// ---------------------------------------------------------------- fused convert
__global__ __launch_bounds__(256) void cvt_all(
    const float* __restrict__ s0, const float* __restrict__ s1,
    const float* __restrict__ s2, const float* __restrict__ s3,
    const float* __restrict__ s4, const float* __restrict__ s5,
    const float* __restrict__ s6, u16* __restrict__ dst)
{
  const int i = (blockIdx.x * 256 + threadIdx.x) * 4;
  const float* sp;
  if      (i <  6291456) sp = s0 + i;
  else if (i <  6881280) sp = s1 + (i - 6291456);
  else if (i <  7471104) sp = s2 + (i - 6881280);
  else if (i <  8060928) sp = s3 + (i - 7471104);
  else if (i <  8650752) sp = s4 + (i - 8060928);
  else if (i < 11010048) sp = s5 + (i - 8650752);
  else                   sp = s6 + (i - 11010048);
  float4 f = *(const float4*)sp;
  u16x4 o = { f2b(f.x), f2b(f.y), f2b(f.z), f2b(f.w) };
  *(u16x4*)(dst + i) = o;
}

// ---------------------------------------------------------------- V transpose: [b,h,s,e] -> [b,h,e,s]
__global__ __launch_bounds__(256) void transpose_v(const u16* __restrict__ v,
                                                   u16* __restrict__ vt){
  __shared__ short t[64][72];
  const int plane = blockIdx.y;
  const u16* vp = v + (size_t)plane * 2048 * 64;
  u16* vtp = vt + (size_t)plane * 2048 * 64;
  const int s0 = blockIdx.x * 64;
#pragma unroll
  for (int j = 0; j < 2; j++){
    int ch = threadIdx.x + 256*j;
    int r = ch >> 3, c = (ch & 7) << 3;
    short8 val = *(const short8*)(vp + (size_t)(s0 + r)*64 + c);
#pragma unroll
    for (int jj = 0; jj < 8; jj++) t[c + jj][r] = val[jj];
  }
  __syncthreads();
#pragma unroll
  for (int j = 0; j < 2; j++){
    int ch = threadIdx.x + 256*j;
    int r = ch >> 3, c = (ch & 7) << 3;
    *(short8*)(vtp + (size_t)r*2048 + s0 + c) = *(const short8*)&t[r][c];
  }
}

enum { EPI_QKV = 0, EPI_FFN1 = 2 };
__device__ __forceinline__ float KSCALE_C(){ return 0.125f * 1.44269504088896340736f; }

// ---------------------------------------------------------------- 128x128 2-phase GEMM, BK=32 (QKV / FFN1)
template<int EPI>
__global__ __launch_bounds__(256) void gemm_bt(
    const u16* __restrict__ A, const u16* __restrict__ Bm,
    int K, int gx,
    u16* __restrict__ outB,
    const float* __restrict__ auxF)  // FFN1: b1
{
  __shared__ __align__(16) short Asm[128][32];
  __shared__ __align__(16) short Bsm[128][32];
  const int tid  = threadIdx.x;
  const int lane = tid & 63;
  const int wid  = tid >> 6;
  const int wr = wid >> 1, wc = wid & 1;
  const int fr = lane & 15, fq = lane >> 4;

  const int nwg = gridDim.x;
  const int lin = blockIdx.x;
  const int wg  = (lin & 7) * (nwg >> 3) + (lin >> 3);
  const int bx = wg % gx, by = wg / gx;
  const int m0 = by * 128, n0 = bx * 128;

  f32x4 acc[4][4];
#pragma unroll
  for (int i = 0; i < 4; i++)
#pragma unroll
    for (int j = 0; j < 4; j++) acc[i][j] = (f32x4){0.f, 0.f, 0.f, 0.f};

  const int lrow = lane >> 2;
  const int lcol = (lane & 3) << 3;

  for (int k0 = 0; k0 < K; k0 += 32) {
    const u16* ga = A  + (size_t)(m0 + wid*32 + lrow) * K + k0 + lcol;
    const u16* gb = Bm + (size_t)(n0 + wid*32 + lrow) * K + k0 + lcol;
    GLD16(ga,                 &Asm[wid*32][0]);
    GLD16(ga + (size_t)16*K,  &Asm[wid*32 + 16][0]);
    GLD16(gb,                 &Bsm[wid*32][0]);
    GLD16(gb + (size_t)16*K,  &Bsm[wid*32 + 16][0]);
    __syncthreads();

    short8 a[4], b[4];
#pragma unroll
    for (int i = 0; i < 4; i++) a[i] = *(const short8*)&Asm[wr*64 + i*16 + fr][fq*8];
#pragma unroll
    for (int j = 0; j < 4; j++) b[j] = *(const short8*)&Bsm[wc*64 + j*16 + fr][fq*8];
    __builtin_amdgcn_s_setprio(1);
#pragma unroll
    for (int i = 0; i < 4; i++)
#pragma unroll
      for (int j = 0; j < 4; j++)
        acc[i][j] = __builtin_amdgcn_mfma_f32_16x16x32_bf16(a[i], b[j], acc[i][j], 0, 0, 0);
    __builtin_amdgcn_s_setprio(0);
    __syncthreads();
  }

#pragma unroll
  for (int i = 0; i < 4; i++) {
    const int row0 = m0 + wr*64 + i*16 + fq*4;
#pragma unroll
    for (int j = 0; j < 4; j++) {
      const int col = n0 + wc*64 + j*16 + fr;
#pragma unroll
      for (int r = 0; r < 4; r++) {
        const int row = row0 + r;
        float val = acc[i][j][r];
        if (EPI == EPI_QKV) {
          int tt = (col >= 1536) ? 2 : (col >= 768 ? 1 : 0);
          int rem = col - tt * 768;
          int h = rem >> 6, e = rem & 63;
          int bb = row >> 11, s = row & 2047;
          size_t idx = (((size_t)(tt*48 + bb*12 + h)) * 2048 + s) * 64 + e;
          if (tt == 1) val *= KSCALE_C();
          outB[idx] = f2b(val);
        } else { // EPI_FFN1
          float o = val + auxF[col];
          o = o > 0.f ? o : 0.f;
          outB[(size_t)row * 3072 + col] = f2b(o);
        }
      }
    }
  }
}

// ---------------------------------------------------------------- 128x128 2-phase split-K GEMM (WO / FFN2)
__global__ __launch_bounds__(256) void gemm_split(
    const u16* __restrict__ A, const u16* __restrict__ Bm,
    int K, int KS, int gx,
    u16* __restrict__ outP)
{
  __shared__ __align__(16) short Asm[128][32];
  __shared__ __align__(16) short Bsm[128][32];
  const int tid  = threadIdx.x;
  const int lane = tid & 63;
  const int wid  = tid >> 6;
  const int wr = wid >> 1, wc = wid & 1;
  const int fr = lane & 15, fq = lane >> 4;

  const int nwg = gridDim.x;
  const int lin = blockIdx.x;
  const int wg  = (lin & 7) * (nwg >> 3) + (lin >> 3);
  const int per = gx * 64;               // blocks per K-slice
  const int ks  = wg / per;
  const int rem = wg % per;
  const int bx = rem % gx, by = rem / gx;
  const int m0 = by * 128, n0 = bx * 128;
  const int kbase = ks * KS;

  f32x4 acc[4][4];
#pragma unroll
  for (int i = 0; i < 4; i++)
#pragma unroll
    for (int j = 0; j < 4; j++) acc[i][j] = (f32x4){0.f, 0.f, 0.f, 0.f};

  const int lrow = lane >> 2;
  const int lcol = (lane & 3) << 3;

  for (int k0 = 0; k0 < KS; k0 += 32) {
    const u16* ga = A  + (size_t)(m0 + wid*32 + lrow) * K + kbase + k0 + lcol;
    const u16* gb = Bm + (size_t)(n0 + wid*32 + lrow) * K + kbase + k0 + lcol;
    GLD16(ga,                 &Asm[wid*32][0]);
    GLD16(ga + (size_t)16*K,  &Asm[wid*32 + 16][0]);
    GLD16(gb,                 &Bsm[wid*32][0]);
    GLD16(gb + (size_t)16*K,  &Bsm[wid*32 + 16][0]);
    __syncthreads();

    short8 a[4], b[4];
#pragma unroll
    for (int i = 0; i < 4; i++) a[i] = *(const short8*)&Asm[wr*64 + i*16 + fr][fq*8];
#pragma unroll
    for (int j = 0; j < 4; j++) b[j] = *(const short8*)&Bsm[wc*64 + j*16 + fr][fq*8];
    __builtin_amdgcn_s_setprio(1);
#pragma unroll
    for (int i = 0; i < 4; i++)
#pragma unroll
      for (int j = 0; j < 4; j++)
        acc[i][j] = __builtin_amdgcn_mfma_f32_16x16x32_bf16(a[i], b[j], acc[i][j], 0, 0, 0);
    __builtin_amdgcn_s_setprio(0);
    __syncthreads();
  }

  u16* op = outP + (size_t)ks * 6291456;   // 8192*768
#pragma unroll
  for (int i = 0; i < 4; i++) {
    const int row0 = m0 + wr*64 + i*16 + fq*4;
#pragma unroll
    for (int j = 0; j < 4; j++) {
      const int col = n0 + wc*64 + j*16 + fr;
#pragma unroll
      for (int r = 0; r < 4; r++)
        op[(size_t)(row0 + r) * 768 + col] = f2b(acc[i][j][r]);
    }
  }
}

// ---------------------------------------------------------------- flash attention: 8 waves, QBLK=128
// 3-buffer LDS + counted vmcnt(2) + raw s_barrier (T4): loads span 2 iterations,
// no vmcnt(0) drain in the main loop. Tail uses clamped re-stage to keep count exact.
__global__ __launch_bounds__(512) void flash_attn(
    const u16* __restrict__ q, const u16* __restrict__ kmat, const u16* __restrict__ vtmat,
    u16* __restrict__ ctx)
{
  const int tid = threadIdx.x;
  const int lane = tid & 63, wid = tid >> 6;       // wid 0..7
  const int fr = lane & 15, fq = lane >> 4;
  const int orig = blockIdx.x;
  const int wg = (orig & 7) * 96 + (orig >> 3);    // bijective XCD swizzle (768=8*96)
  const int qb = wg & 15;
  const int ph = wg >> 4;
  const size_t plane = (size_t)ph * 2048 * 64;
  const u16* qp  = q + plane;
  const u16* kp  = kmat + plane;
  const u16* vtp = vtmat + plane;

  __shared__ __align__(16) short Ksm[3][64][64];
  __shared__ __align__(16) short Vsm[3][64][64];

  const int qr0 = qb*128 + wid*16;
  const short8 aq0 = *(const short8*)(qp + (size_t)(qr0 + fr)*64 + fq*8);
  const short8 aq1 = *(const short8*)(qp + (size_t)(qr0 + fr)*64 + 32 + fq*8);

  short8 vones;
#pragma unroll
  for (int j = 0; j < 8; j++) vones[j] = (short)0x3F80;   // bf16 1.0

  const int rA = wid*8 + (lane >> 3);
  const int cA = (((lane & 7) ^ ((rA & 3) | (((rA >> 3) & 1) << 2)))) * 8;

#define STAGE(B, KT) do { \
    GLD16(kp  + (size_t)((KT)*64 + rA)*64 + cA,  &Ksm[B][wid*8][0]); \
    GLD16(vtp + (size_t)rA*2048 + (KT)*64 + cA,  &Vsm[B][wid*8][0]); \
  } while(0)

  f32x4 o[4];
#pragma unroll
  for (int eb = 0; eb < 4; eb++) o[eb] = (f32x4){0.f, 0.f, 0.f, 0.f};
  float m = -1e30f, l = 0.f;
  const f32x4 zero = (f32x4){0.f, 0.f, 0.f, 0.f};

  const int fK  = (fr & 3) | (((fr >> 2) & 1) << 2);
  const int kc0 = ((fq    ) ^ fK) * 8;
  const int kc1 = ((4 + fq) ^ fK) * 8;
  const int krow = (fr & 3) + 8 * (fr >> 2);
  const int fV  = (fr & 3) | (((fr >> 3) & 1) << 2);
  const int vc0 = ((fq    ) ^ fV) * 8;
  const int vc1 = ((4 + fq) ^ fV) * 8;

  STAGE(0, 0);     // 2 outstanding
  STAGE(1, 1);     // 4 outstanding

  for (int kt = 0; kt < 32; ++kt) {
    const int cur = kt % 3;
    // tile-kt's own loads landed (tile kt+1's 2 remain in flight); barrier makes it block-wide
    asm volatile("s_waitcnt vmcnt(2)" ::: "memory");
    __builtin_amdgcn_s_barrier();
    asm volatile("" ::: "memory");
    {
      const int t2 = (kt + 2 < 32) ? kt + 2 : 31;  // clamped re-stage keeps vmcnt count exact
      STAGE((kt + 2) % 3, t2);
    }

    f32x4 st[2][2];
    __builtin_amdgcn_s_setprio(1);
#pragma unroll
    for (int h = 0; h < 2; h++)
#pragma unroll
      for (int c = 0; c < 2; c++) {
        const short* kr = &Ksm[cur][32*h + 4*c + krow][0];
        short8 kf0 = *(const short8*)(kr + kc0);
        short8 kf1 = *(const short8*)(kr + kc1);
        f32x4 a = __builtin_amdgcn_mfma_f32_16x16x32_bf16(kf0, aq0, zero, 0, 0, 0);
        st[h][c]  = __builtin_amdgcn_mfma_f32_16x16x32_bf16(kf1, aq1, a,    0, 0, 0);
      }
    __builtin_amdgcn_s_setprio(0);

    float t0 = fmaxf(fmaxf(st[0][0][0], st[0][0][1]), st[0][0][2]);
    float t1 = fmaxf(fmaxf(st[0][0][3], st[0][1][0]), st[0][1][1]);
    float t2m = fmaxf(fmaxf(st[0][1][2], st[0][1][3]), st[1][0][0]);
    float t3 = fmaxf(fmaxf(st[1][0][1], st[1][0][2]), st[1][0][3]);
    float t4 = fmaxf(fmaxf(st[1][1][0], st[1][1][1]), st[1][1][2]);
    float u0 = fmaxf(fmaxf(t0, t1), st[1][1][3]);
    float u1 = fmaxf(fmaxf(t2m, t3), t4);
    float lm = fmaxf(u0, u1);
    lm = fmaxf(lm, __shfl_xor(lm, 16));
    lm = fmaxf(lm, __shfl_xor(lm, 32));

    if (!__all(lm <= m + 8.f)) {
      float nm = fmaxf(m, lm);
      float corr = EXP2(m - nm);
      m = nm;
      l *= corr;
#pragma unroll
      for (int eb = 0; eb < 4; eb++)
#pragma unroll
        for (int r = 0; r < 4; r++) o[eb][r] *= corr;
    }

    float p[2][2][4];
#pragma unroll
    for (int h = 0; h < 2; h++)
#pragma unroll
      for (int c = 0; c < 2; c++)
#pragma unroll
        for (int r = 0; r < 4; r++)
          p[h][c][r] = EXP2(st[h][c][r] - m);

    union { u32 u[4]; short8 s8; } pf0, pf1;
    pf0.u[0] = pkbf(p[0][0][0], p[0][0][1]);
    pf0.u[1] = pkbf(p[0][0][2], p[0][0][3]);
    pf0.u[2] = pkbf(p[0][1][0], p[0][1][1]);
    pf0.u[3] = pkbf(p[0][1][2], p[0][1][3]);
    pf1.u[0] = pkbf(p[1][0][0], p[1][0][1]);
    pf1.u[1] = pkbf(p[1][0][2], p[1][0][3]);
    pf1.u[2] = pkbf(p[1][1][0], p[1][1][1]);
    pf1.u[3] = pkbf(p[1][1][2], p[1][1][3]);

    __builtin_amdgcn_s_setprio(1);
    f32x4 ol = __builtin_amdgcn_mfma_f32_16x16x32_bf16(vones, pf0.s8, zero, 0, 0, 0);
    ol       = __builtin_amdgcn_mfma_f32_16x16x32_bf16(vones, pf1.s8, ol,   0, 0, 0);
#pragma unroll
    for (int eb = 0; eb < 4; eb++) {
      const short* vr = &Vsm[cur][eb*16 + fr][0];
      o[eb] = __builtin_amdgcn_mfma_f32_16x16x32_bf16(*(const short8*)(vr + vc0), pf0.s8, o[eb], 0, 0, 0);
      o[eb] = __builtin_amdgcn_mfma_f32_16x16x32_bf16(*(const short8*)(vr + vc1), pf1.s8, o[eb], 0, 0, 0);
    }
    __builtin_amdgcn_s_setprio(0);
    l += ol[0];
  }
#undef STAGE

  const float inv = 1.0f / l;
  const int s = qr0 + fr;
  u16* cp = ctx + ((size_t)((ph/12)*2048 + s)) * 768 + (ph%12)*64;
#pragma unroll
  for (int eb = 0; eb < 4; eb++) {
    u16x4 w = { f2b(o[eb][0]*inv), f2b(o[eb][1]*inv), f2b(o[eb][2]*inv), f2b(o[eb][3]*inv) };
    *(u16x4*)(cp + eb*16 + fq*4) = w;
  }
}

// ---------------------------------------------------------------- layernorm over p0+p1+extra(+bias)
template<int HASBIAS, int F32OUT>
__global__ __launch_bounds__(256) void ln_add_k(
    const u16* __restrict__ p0, const u16* __restrict__ p1, const u16* __restrict__ extra,
    const float* __restrict__ bias,
    const float* __restrict__ g, const float* __restrict__ be, void* __restrict__ outp)
{
  const int lane = threadIdx.x & 63, wid = threadIdx.x >> 6;
  const int row = blockIdx.x * 4 + wid;
  const size_t base = (size_t)row * 768;
  float v[12];
  float s = 0.f, s2 = 0.f;
#pragma unroll
  for (int i = 0; i < 6; i++) {
    int c = i*128 + lane*2;
    ushort2 a0 = *(const ushort2*)(p0 + base + c);
    ushort2 a1 = *(const ushort2*)(p1 + base + c);
    ushort2 ax = *(const ushort2*)(extra + base + c);
    float v0 = b2f(a0.x) + b2f(a1.x) + b2f(ax.x);
    float v1 = b2f(a0.y) + b2f(a1.y) + b2f(ax.y);
    if (HASBIAS) { v0 += bias[c]; v1 += bias[c+1]; }
    v[2*i] = v0; v[2*i+1] = v1;
    s += v0 + v1;
    s2 += v0*v0 + v1*v1;
  }
#pragma unroll
  for (int msk = 1; msk < 64; msk <<= 1) { s += __shfl_xor(s, msk); s2 += __shfl_xor(s2, msk); }
  const float mu = s * (1.f/768.f);
  const float var = s2 * (1.f/768.f) - mu*mu;
  const float rstd = rsqrtf(var + 1e-5f);
#pragma unroll
  for (int i = 0; i < 6; i++) {
    int c = i*128 + lane*2;
    float o0 = (v[2*i]   - mu) * rstd * g[c]   + be[c];
    float o1 = (v[2*i+1] - mu) * rstd * g[c+1] + be[c+1];
    if (F32OUT) {
      float2 w = { o0, o1 };
      *(float2*)((float*)outp + base + c) = w;
    } else {
      ushort2 w = { f2b(o0), f2b(o1) };
      *(ushort2*)((u16*)outp + base + c) = w;
    }
  }
}

// ---------------------------------------------------------------- launch
extern "C" void kernel_launch(void* const* d_in, const int* in_sizes, int n_in,
                              void* d_out, int out_size, void* d_ws, size_t ws_size,
                              hipStream_t stream)
{
  const float* x   = (const float*)d_in[0];
  const float* Wq  = (const float*)d_in[1];
  const float* Wk  = (const float*)d_in[2];
  const float* Wv  = (const float*)d_in[3];
  const float* Wo  = (const float*)d_in[4];
  const float* W1  = (const float*)d_in[5];
  const float* b1  = (const float*)d_in[6];
  const float* W2  = (const float*)d_in[7];
  const float* b2  = (const float*)d_in[8];
  const float* g1  = (const float*)d_in[9];
  const float* be1 = (const float*)d_in[10];
  const float* g2  = (const float*)d_in[11];
  const float* be2 = (const float*)d_in[12];
  float* out = (float*)d_out;

  char* ws = (char*)d_ws;
  u16* xb     = (u16*)(ws + 0);
  u16* Wqkv_b = (u16*)(ws + 12582912);
  u16* Wo_b   = (u16*)(ws + 16121856);
  u16* W1_b   = (u16*)(ws + 17301504);
  u16* W2_b   = (u16*)(ws + 22020096);
  u16* qkv    = (u16*)(ws + 26738688);
  u16* ctxb   = (u16*)(ws + 64487424);
  u16* hidden = (u16*)(ws + 26738688);     // alias qkv+ctx
  u16* vt     = (u16*)(ws + 77070336);     // V^T (dead after flash)
  u16* part   = (u16*)(ws + 77070336);     // split-K partials [2][8192][768] bf16 (alias vt)
  u16* hb     = (u16*)(ws + 102236160);

  cvt_all<<<dim3(13056), 256, 0, stream>>>(x, Wq, Wk, Wv, Wo, W1, W2, (u16*)ws);

  // QKV: [8192,768] @ [2304,768]^T  (grid 18*64=1152)
  gemm_bt<EPI_QKV><<<dim3(1152), 256, 0, stream>>>(
      xb, Wqkv_b, 768, 18, qkv, nullptr);

  u16* qb_ = qkv;
  u16* kb_ = qkv + 6291456;
  u16* vb_ = qkv + 12582912;

  transpose_v<<<dim3(32, 48), 256, 0, stream>>>(vb_, vt);

  // flash: 8 waves/block, QBLK=128, 3-buf counted vmcnt (grid 768 = 3.0/CU)
  flash_attn<<<dim3(768), 512, 0, stream>>>(qb_, kb_, vt, ctxb);

  u16* p0 = part;
  u16* p1 = part + 6291456;

  // WO split-K=2: [8192,768] @ [768,768]^T -> partials (grid 768 = 3.0/CU, 12 iters/block)
  gemm_split<<<dim3(768), 256, 0, stream>>>(ctxb, Wo_b, 768, 384, 6, part);

  // LN1: LN(p0 + p1 + x) -> hb
  ln_add_k<0, 0><<<2048, 256, 0, stream>>>(p0, p1, xb, nullptr, g1, be1, hb);

  // FFN1: [8192,768] @ [3072,768]^T  (grid 24*64=1536)
  gemm_bt<EPI_FFN1><<<dim3(1536), 256, 0, stream>>>(
      hb, W1_b, 768, 24, hidden, b1);

  // FFN2 split-K=2: [8192,3072] @ [768,3072]^T -> partials (grid 768, 48 iters/block)
  gemm_split<<<dim3(768), 256, 0, stream>>>(hidden, W2_b, 3072, 1536, 6, part);

  // LN2: LN(p0 + p1 + hb + b2) -> out (f32)
  ln_add_k<1, 1><<<2048, 256, 0, stream>>>(p0, p1, hb, b2, g2, be2, out);
}

// Round 18
// 276.162 us; speedup vs baseline: 1.0052x; 1.0052x over previous
//
#include <hip/hip_runtime.h>

typedef unsigned short u16;
typedef unsigned int u32;
typedef __attribute__((ext_vector_type(8))) short short8;
typedef __attribute__((ext_vector_type(4))) float f32x4;
typedef __attribute__((ext_vector_type(4))) unsigned short u16x4;

extern "C" __device__ float __ocml_native_exp2_f32(float);
#define EXP2(x) __ocml_native_exp2_f32(x)

__device__ __forceinline__ float b2f(u16 u){
  union { float f; unsigned int i; } c; c.i = ((unsigned int)u) << 16; return c.f;
}
__device__ __forceinline__ u16 f2b(float f){
  union { float f; unsigned int i; } c; c.f = f;
  unsigned int i = c.i;
  unsigned int r = (i + 0x7FFFu + ((i >> 16) & 1u)) >> 16;
  return (u16)r;
}

#define GLD16(gp, lp) __builtin_amdgcn_global_load_lds( \
    (const __attribute__((address_space(1))) void*)(gp), \
    (__attribute__((address_space(3))) void*)(lp), 16, 0, 0)

__device__ __forceinline__ u32 pkbf(float lo, float hi){
  u32 r;
  asm volatile("v_cvt_pk_bf16_f32 %0, %1, %2" : "=v"(r) : "v"(lo), "v"(hi));
  return r;
}

// ---------------------------------------------------------------- fused convert
__global__ __launch_bounds__(256) void cvt_all(
    const float* __restrict__ s0, const float* __restrict__ s1,
    const float* __restrict__ s2, const float* __restrict__ s3,
    const float* __restrict__ s4, const float* __restrict__ s5,
    const float* __restrict__ s6, u16* __restrict__ dst)
{
  const int i = (blockIdx.x * 256 + threadIdx.x) * 4;
  const float* sp;
  if      (i <  6291456) sp = s0 + i;
  else if (i <  6881280) sp = s1 + (i - 6291456);
  else if (i <  7471104) sp = s2 + (i - 6881280);
  else if (i <  8060928) sp = s3 + (i - 7471104);
  else if (i <  8650752) sp = s4 + (i - 8060928);
  else if (i < 11010048) sp = s5 + (i - 8650752);
  else                   sp = s6 + (i - 11010048);
  float4 f = *(const float4*)sp;
  u16x4 o = { f2b(f.x), f2b(f.y), f2b(f.z), f2b(f.w) };
  *(u16x4*)(dst + i) = o;
}

// ---------------------------------------------------------------- V transpose: packed qkv col-block [1536,2304) -> vt[b,h,e,s]
__global__ __launch_bounds__(256) void transpose_v(const u16* __restrict__ qkv,
                                                   u16* __restrict__ vt){
  __shared__ short t[64][72];
  const int plane = blockIdx.y;                 // b*12 + h
  const int b = plane / 12, h = plane % 12;
  const u16* vp = qkv + (size_t)b * 2048 * 2304 + 1536 + h * 64;
  u16* vtp = vt + (size_t)plane * 2048 * 64;
  const int s0 = blockIdx.x * 64;
#pragma unroll
  for (int j = 0; j < 2; j++){
    int ch = threadIdx.x + 256*j;
    int r = ch >> 3, c = (ch & 7) << 3;
    short8 val = *(const short8*)(vp + (size_t)(s0 + r)*2304 + c);
#pragma unroll
    for (int jj = 0; jj < 8; jj++) t[c + jj][r] = val[jj];
  }
  __syncthreads();
#pragma unroll
  for (int j = 0; j < 2; j++){
    int ch = threadIdx.x + 256*j;
    int r = ch >> 3, c = (ch & 7) << 3;
    *(short8*)(vtp + (size_t)r*2048 + s0 + c) = *(const short8*)&t[r][c];
  }
}

enum { EPI_QKV = 0, EPI_FFN1 = 2 };
__device__ __forceinline__ float KSCALE_C(){ return 0.125f * 1.44269504088896340736f; }

// ---------------------------------------------------------------- 128x128 2-phase GEMM, BK=32 (QKV / FFN1)
// QKV: plain row-major [8192,2304] output (q|k|v packed by column), k cols pre-scaled.
template<int EPI>
__global__ __launch_bounds__(256) void gemm_bt(
    const u16* __restrict__ A, const u16* __restrict__ Bm,
    int K, int gx, int ldc,
    u16* __restrict__ outB,
    const float* __restrict__ auxF)  // FFN1: b1
{
  __shared__ __align__(16) short Asm[128][32];
  __shared__ __align__(16) short Bsm[128][32];
  const int tid  = threadIdx.x;
  const int lane = tid & 63;
  const int wid  = tid >> 6;
  const int wr = wid >> 1, wc = wid & 1;
  const int fr = lane & 15, fq = lane >> 4;

  const int nwg = gridDim.x;
  const int lin = blockIdx.x;
  const int wg  = (lin & 7) * (nwg >> 3) + (lin >> 3);
  const int bx = wg % gx, by = wg / gx;
  const int m0 = by * 128, n0 = bx * 128;

  f32x4 acc[4][4];
#pragma unroll
  for (int i = 0; i < 4; i++)
#pragma unroll
    for (int j = 0; j < 4; j++) acc[i][j] = (f32x4){0.f, 0.f, 0.f, 0.f};

  const int lrow = lane >> 2;
  const int lcol = (lane & 3) << 3;

  for (int k0 = 0; k0 < K; k0 += 32) {
    const u16* ga = A  + (size_t)(m0 + wid*32 + lrow) * K + k0 + lcol;
    const u16* gb = Bm + (size_t)(n0 + wid*32 + lrow) * K + k0 + lcol;
    GLD16(ga,                 &Asm[wid*32][0]);
    GLD16(ga + (size_t)16*K,  &Asm[wid*32 + 16][0]);
    GLD16(gb,                 &Bsm[wid*32][0]);
    GLD16(gb + (size_t)16*K,  &Bsm[wid*32 + 16][0]);
    __syncthreads();

    short8 a[4], b[4];
#pragma unroll
    for (int i = 0; i < 4; i++) a[i] = *(const short8*)&Asm[wr*64 + i*16 + fr][fq*8];
#pragma unroll
    for (int j = 0; j < 4; j++) b[j] = *(const short8*)&Bsm[wc*64 + j*16 + fr][fq*8];
    __builtin_amdgcn_s_setprio(1);
#pragma unroll
    for (int i = 0; i < 4; i++)
#pragma unroll
      for (int j = 0; j < 4; j++)
        acc[i][j] = __builtin_amdgcn_mfma_f32_16x16x32_bf16(a[i], b[j], acc[i][j], 0, 0, 0);
    __builtin_amdgcn_s_setprio(0);
    __syncthreads();
  }

#pragma unroll
  for (int i = 0; i < 4; i++) {
    const int row0 = m0 + wr*64 + i*16 + fq*4;
#pragma unroll
    for (int j = 0; j < 4; j++) {
      const int col = n0 + wc*64 + j*16 + fr;
      const float ks = (EPI == EPI_QKV && col >= 768 && col < 1536) ? KSCALE_C() : 1.0f;
#pragma unroll
      for (int r = 0; r < 4; r++) {
        const int row = row0 + r;
        float val = acc[i][j][r];
        if (EPI == EPI_QKV) {
          outB[(size_t)row * ldc + col] = f2b(val * ks);
        } else { // EPI_FFN1
          float o = val + auxF[col];
          o = o > 0.f ? o : 0.f;
          outB[(size_t)row * ldc + col] = f2b(o);
        }
      }
    }
  }
}

// ---------------------------------------------------------------- 128x128 2-phase split-K GEMM (WO / FFN2)
__global__ __launch_bounds__(256) void gemm_split(
    const u16* __restrict__ A, const u16* __restrict__ Bm,
    int K, int KS, int gx,
    u16* __restrict__ outP)
{
  __shared__ __align__(16) short Asm[128][32];
  __shared__ __align__(16) short Bsm[128][32];
  const int tid  = threadIdx.x;
  const int lane = tid & 63;
  const int wid  = tid >> 6;
  const int wr = wid >> 1, wc = wid & 1;
  const int fr = lane & 15, fq = lane >> 4;

  const int nwg = gridDim.x;
  const int lin = blockIdx.x;
  const int wg  = (lin & 7) * (nwg >> 3) + (lin >> 3);
  const int per = gx * 64;               // blocks per K-slice
  const int ks  = wg / per;
  const int rem = wg % per;
  const int bx = rem % gx, by = rem / gx;
  const int m0 = by * 128, n0 = bx * 128;
  const int kbase = ks * KS;

  f32x4 acc[4][4];
#pragma unroll
  for (int i = 0; i < 4; i++)
#pragma unroll
    for (int j = 0; j < 4; j++) acc[i][j] = (f32x4){0.f, 0.f, 0.f, 0.f};

  const int lrow = lane >> 2;
  const int lcol = (lane & 3) << 3;

  for (int k0 = 0; k0 < KS; k0 += 32) {
    const u16* ga = A  + (size_t)(m0 + wid*32 + lrow) * K + kbase + k0 + lcol;
    const u16* gb = Bm + (size_t)(n0 + wid*32 + lrow) * K + kbase + k0 + lcol;
    GLD16(ga,                 &Asm[wid*32][0]);
    GLD16(ga + (size_t)16*K,  &Asm[wid*32 + 16][0]);
    GLD16(gb,                 &Bsm[wid*32][0]);
    GLD16(gb + (size_t)16*K,  &Bsm[wid*32 + 16][0]);
    __syncthreads();

    short8 a[4], b[4];
#pragma unroll
    for (int i = 0; i < 4; i++) a[i] = *(const short8*)&Asm[wr*64 + i*16 + fr][fq*8];
#pragma unroll
    for (int j = 0; j < 4; j++) b[j] = *(const short8*)&Bsm[wc*64 + j*16 + fr][fq*8];
    __builtin_amdgcn_s_setprio(1);
#pragma unroll
    for (int i = 0; i < 4; i++)
#pragma unroll
      for (int j = 0; j < 4; j++)
        acc[i][j] = __builtin_amdgcn_mfma_f32_16x16x32_bf16(a[i], b[j], acc[i][j], 0, 0, 0);
    __builtin_amdgcn_s_setprio(0);
    __syncthreads();
  }

  u16* op = outP + (size_t)ks * 6291456;   // 8192*768
#pragma unroll
  for (int i = 0; i < 4; i++) {
    const int row0 = m0 + wr*64 + i*16 + fq*4;
#pragma unroll
    for (int j = 0; j < 4; j++) {
      const int col = n0 + wc*64 + j*16 + fr;
#pragma unroll
      for (int r = 0; r < 4; r++)
        op[(size_t)(row0 + r) * 768 + col] = f2b(acc[i][j][r]);
    }
  }
}

// ---------------------------------------------------------------- flash attention: 8 waves, QBLK=128 (r16 proven, packed-qkv addressing)
__global__ __launch_bounds__(512) void flash_attn(
    const u16* __restrict__ qkv, const u16* __restrict__ vtmat,
    u16* __restrict__ ctx)
{
  const int tid = threadIdx.x;
  const int lane = tid & 63, wid = tid >> 6;       // wid 0..7
  const int fr = lane & 15, fq = lane >> 4;
  const int orig = blockIdx.x;
  const int wg = (orig & 7) * 96 + (orig >> 3);    // bijective XCD swizzle (768=8*96)
  const int qb = wg & 15;
  const int ph = wg >> 4;
  const int b = ph / 12, h = ph % 12;
  const u16* qp  = qkv + (size_t)b * 2048 * 2304 + h * 64;          // q cols [0,768)
  const u16* kp  = qkv + (size_t)b * 2048 * 2304 + 768 + h * 64;    // k cols [768,1536)
  const u16* vtp = vtmat + (size_t)ph * 2048 * 64;

  __shared__ __align__(16) short Ksm[2][64][64];
  __shared__ __align__(16) short Vsm[2][64][64];

  const int qr0 = qb*128 + wid*16;
  const short8 aq0 = *(const short8*)(qp + (size_t)(qr0 + fr)*2304 + fq*8);
  const short8 aq1 = *(const short8*)(qp + (size_t)(qr0 + fr)*2304 + 32 + fq*8);

  short8 vones;
#pragma unroll
  for (int j = 0; j < 8; j++) vones[j] = (short)0x3F80;   // bf16 1.0

  const int rA = wid*8 + (lane >> 3);
  const int cA = (((lane & 7) ^ ((rA & 3) | (((rA >> 3) & 1) << 2)))) * 8;

#define STAGE(B, KT) do { \
    GLD16(kp  + (size_t)((KT)*64 + rA)*2304 + cA,  &Ksm[B][wid*8][0]); \
    GLD16(vtp + (size_t)rA*2048 + (KT)*64 + cA,    &Vsm[B][wid*8][0]); \
  } while(0)

  f32x4 o[4];
#pragma unroll
  for (int eb = 0; eb < 4; eb++) o[eb] = (f32x4){0.f, 0.f, 0.f, 0.f};
  float m = -1e30f, l = 0.f;
  const f32x4 zero = (f32x4){0.f, 0.f, 0.f, 0.f};

  STAGE(0, 0);
  __syncthreads();

  const int fK  = (fr & 3) | (((fr >> 2) & 1) << 2);
  const int kc0 = ((fq    ) ^ fK) * 8;
  const int kc1 = ((4 + fq) ^ fK) * 8;
  const int krow = (fr & 3) + 8 * (fr >> 2);
  const int fV  = (fr & 3) | (((fr >> 3) & 1) << 2);
  const int vc0 = ((fq    ) ^ fV) * 8;
  const int vc1 = ((4 + fq) ^ fV) * 8;

  int buf = 0;
  for (int kt = 0; kt < 32; ++kt) {
    if (kt < 31) STAGE(buf ^ 1, kt + 1);

    f32x4 st[2][2];
    __builtin_amdgcn_s_setprio(1);
#pragma unroll
    for (int h2 = 0; h2 < 2; h2++)
#pragma unroll
      for (int c = 0; c < 2; c++) {
        const short* kr = &Ksm[buf][32*h2 + 4*c + krow][0];
        short8 kf0 = *(const short8*)(kr + kc0);
        short8 kf1 = *(const short8*)(kr + kc1);
        f32x4 a = __builtin_amdgcn_mfma_f32_16x16x32_bf16(kf0, aq0, zero, 0, 0, 0);
        st[h2][c] = __builtin_amdgcn_mfma_f32_16x16x32_bf16(kf1, aq1, a,    0, 0, 0);
      }
    __builtin_amdgcn_s_setprio(0);

    float t0 = fmaxf(fmaxf(st[0][0][0], st[0][0][1]), st[0][0][2]);
    float t1 = fmaxf(fmaxf(st[0][0][3], st[0][1][0]), st[0][1][1]);
    float t2 = fmaxf(fmaxf(st[0][1][2], st[0][1][3]), st[1][0][0]);
    float t3 = fmaxf(fmaxf(st[1][0][1], st[1][0][2]), st[1][0][3]);
    float t4 = fmaxf(fmaxf(st[1][1][0], st[1][1][1]), st[1][1][2]);
    float u0 = fmaxf(fmaxf(t0, t1), st[1][1][3]);
    float u1 = fmaxf(fmaxf(t2, t3), t4);
    float lm = fmaxf(u0, u1);
    lm = fmaxf(lm, __shfl_xor(lm, 16));
    lm = fmaxf(lm, __shfl_xor(lm, 32));

    if (!__all(lm <= m + 8.f)) {
      float nm = fmaxf(m, lm);
      float corr = EXP2(m - nm);
      m = nm;
      l *= corr;
#pragma unroll
      for (int eb = 0; eb < 4; eb++)
#pragma unroll
        for (int r = 0; r < 4; r++) o[eb][r] *= corr;
    }

    float p[2][2][4];
#pragma unroll
    for (int h2 = 0; h2 < 2; h2++)
#pragma unroll
      for (int c = 0; c < 2; c++)
#pragma unroll
        for (int r = 0; r < 4; r++)
          p[h2][c][r] = EXP2(st[h2][c][r] - m);

    union { u32 u[4]; short8 s8; } pf0, pf1;
    pf0.u[0] = pkbf(p[0][0][0], p[0][0][1]);
    pf0.u[1] = pkbf(p[0][0][2], p[0][0][3]);
    pf0.u[2] = pkbf(p[0][1][0], p[0][1][1]);
    pf0.u[3] = pkbf(p[0][1][2], p[0][1][3]);
    pf1.u[0] = pkbf(p[1][0][0], p[1][0][1]);
    pf1.u[1] = pkbf(p[1][0][2], p[1][0][3]);
    pf1.u[2] = pkbf(p[1][1][0], p[1][1][1]);
    pf1.u[3] = pkbf(p[1][1][2], p[1][1][3]);

    __builtin_amdgcn_s_setprio(1);
    f32x4 ol = __builtin_amdgcn_mfma_f32_16x16x32_bf16(vones, pf0.s8, zero, 0, 0, 0);
    ol       = __builtin_amdgcn_mfma_f32_16x16x32_bf16(vones, pf1.s8, ol,   0, 0, 0);
#pragma unroll
    for (int eb = 0; eb < 4; eb++) {
      const short* vr = &Vsm[buf][eb*16 + fr][0];
      o[eb] = __builtin_amdgcn_mfma_f32_16x16x32_bf16(*(const short8*)(vr + vc0), pf0.s8, o[eb], 0, 0, 0);
      o[eb] = __builtin_amdgcn_mfma_f32_16x16x32_bf16(*(const short8*)(vr + vc1), pf1.s8, o[eb], 0, 0, 0);
    }
    __builtin_amdgcn_s_setprio(0);
    l += ol[0];

    __syncthreads();
    buf ^= 1;
  }
#undef STAGE

  const float inv = 1.0f / l;
  const int s = qr0 + fr;
  u16* cp = ctx + ((size_t)(b*2048 + s)) * 768 + h*64;
#pragma unroll
  for (int eb = 0; eb < 4; eb++) {
    u16x4 w = { f2b(o[eb][0]*inv), f2b(o[eb][1]*inv), f2b(o[eb][2]*inv), f2b(o[eb][3]*inv) };
    *(u16x4*)(cp + eb*16 + fq*4) = w;
  }
}

// ---------------------------------------------------------------- layernorm over p0+p1+extra(+bias)
template<int HASBIAS, int F32OUT>
__global__ __launch_bounds__(256) void ln_add_k(
    const u16* __restrict__ p0, const u16* __restrict__ p1, const u16* __restrict__ extra,
    const float* __restrict__ bias,
    const float* __restrict__ g, const float* __restrict__ be, void* __restrict__ outp)
{
  const int lane = threadIdx.x & 63, wid = threadIdx.x >> 6;
  const int row = blockIdx.x * 4 + wid;
  const size_t base = (size_t)row * 768;
  float v[12];
  float s = 0.f, s2 = 0.f;
#pragma unroll
  for (int i = 0; i < 6; i++) {
    int c = i*128 + lane*2;
    ushort2 a0 = *(const ushort2*)(p0 + base + c);
    ushort2 a1 = *(const ushort2*)(p1 + base + c);
    ushort2 ax = *(const ushort2*)(extra + base + c);
    float v0 = b2f(a0.x) + b2f(a1.x) + b2f(ax.x);
    float v1 = b2f(a0.y) + b2f(a1.y) + b2f(ax.y);
    if (HASBIAS) { v0 += bias[c]; v1 += bias[c+1]; }
    v[2*i] = v0; v[2*i+1] = v1;
    s += v0 + v1;
    s2 += v0*v0 + v1*v1;
  }
#pragma unroll
  for (int msk = 1; msk < 64; msk <<= 1) { s += __shfl_xor(s, msk); s2 += __shfl_xor(s2, msk); }
  const float mu = s * (1.f/768.f);
  const float var = s2 * (1.f/768.f) - mu*mu;
  const float rstd = rsqrtf(var + 1e-5f);
#pragma unroll
  for (int i = 0; i < 6; i++) {
    int c = i*128 + lane*2;
    float o0 = (v[2*i]   - mu) * rstd * g[c]   + be[c];
    float o1 = (v[2*i+1] - mu) * rstd * g[c+1] + be[c+1];
    if (F32OUT) {
      float2 w = { o0, o1 };
      *(float2*)((float*)outp + base + c) = w;
    } else {
      ushort2 w = { f2b(o0), f2b(o1) };
      *(ushort2*)((u16*)outp + base + c) = w;
    }
  }
}

// ---------------------------------------------------------------- launch
extern "C" void kernel_launch(void* const* d_in, const int* in_sizes, int n_in,
                              void* d_out, int out_size, void* d_ws, size_t ws_size,
                              hipStream_t stream)
{
  const float* x   = (const float*)d_in[0];
  const float* Wq  = (const float*)d_in[1];
  const float* Wk  = (const float*)d_in[2];
  const float* Wv  = (const float*)d_in[3];
  const float* Wo  = (const float*)d_in[4];
  const float* W1  = (const float*)d_in[5];
  const float* b1  = (const float*)d_in[6];
  const float* W2  = (const float*)d_in[7];
  const float* b2  = (const float*)d_in[8];
  const float* g1  = (const float*)d_in[9];
  const float* be1 = (const float*)d_in[10];
  const float* g2  = (const float*)d_in[11];
  const float* be2 = (const float*)d_in[12];
  float* out = (float*)d_out;

  char* ws = (char*)d_ws;
  u16* xb     = (u16*)(ws + 0);
  u16* Wqkv_b = (u16*)(ws + 12582912);
  u16* Wo_b   = (u16*)(ws + 16121856);
  u16* W1_b   = (u16*)(ws + 17301504);
  u16* W2_b   = (u16*)(ws + 22020096);
  u16* qkv    = (u16*)(ws + 26738688);     // packed [8192][2304]
  u16* ctxb   = (u16*)(ws + 64487424);
  u16* hidden = (u16*)(ws + 26738688);     // alias qkv+ctx
  u16* vt     = (u16*)(ws + 77070336);     // V^T [b,h,e,s] (dead after flash)
  u16* part   = (u16*)(ws + 77070336);     // split-K partials [2][8192][768] bf16 (alias vt)
  u16* hb     = (u16*)(ws + 102236160);

  cvt_all<<<dim3(13056), 256, 0, stream>>>(x, Wq, Wk, Wv, Wo, W1, W2, (u16*)ws);

  // QKV: [8192,768] @ [2304,768]^T -> packed [8192,2304] (grid 18*64=1152)
  gemm_bt<EPI_QKV><<<dim3(1152), 256, 0, stream>>>(
      xb, Wqkv_b, 768, 18, 2304, qkv, nullptr);

  transpose_v<<<dim3(32, 48), 256, 0, stream>>>(qkv, vt);

  // flash: 8 waves/block, QBLK=128 (grid 768 = 3.0/CU)
  flash_attn<<<dim3(768), 512, 0, stream>>>(qkv, vt, ctxb);

  u16* p0 = part;
  u16* p1 = part + 6291456;

  // WO split-K=2: [8192,768] @ [768,768]^T -> partials (grid 768 = 3.0/CU, 12 iters/block)
  gemm_split<<<dim3(768), 256, 0, stream>>>(ctxb, Wo_b, 768, 384, 6, part);

  // LN1: LN(p0 + p1 + x) -> hb
  ln_add_k<0, 0><<<2048, 256, 0, stream>>>(p0, p1, xb, nullptr, g1, be1, hb);

  // FFN1: [8192,768] @ [3072,768]^T  (grid 24*64=1536)
  gemm_bt<EPI_FFN1><<<dim3(1536), 256, 0, stream>>>(
      hb, W1_b, 768, 24, 3072, hidden, b1);

  // FFN2 split-K=2: [8192,3072] @ [768,3072]^T -> partials (grid 768, 48 iters/block)
  gemm_split<<<dim3(768), 256, 0, stream>>>(hidden, W2_b, 3072, 1536, 6, part);

  // LN2: LN(p0 + p1 + hb + b2) -> out (f32)
  ln_add_k<1, 1><<<2048, 256, 0, stream>>>(p0, p1, hb, b2, g2, be2, out);
}

// Round 19
// 275.765 us; speedup vs baseline: 1.0067x; 1.0014x over previous
//
#include <hip/hip_runtime.h>

typedef unsigned short u16;
typedef unsigned int u32;
typedef __attribute__((ext_vector_type(8))) short short8;
typedef __attribute__((ext_vector_type(4))) float f32x4;
typedef __attribute__((ext_vector_type(4))) unsigned short u16x4;

extern "C" __device__ float __ocml_native_exp2_f32(float);
#define EXP2(x) __ocml_native_exp2_f32(x)

__device__ __forceinline__ float b2f(u16 u){
  union { float f; unsigned int i; } c; c.i = ((unsigned int)u) << 16; return c.f;
}
__device__ __forceinline__ u16 f2b(float f){
  union { float f; unsigned int i; } c; c.f = f;
  unsigned int i = c.i;
  unsigned int r = (i + 0x7FFFu + ((i >> 16) & 1u)) >> 16;
  return (u16)r;
}

#define GLD16(gp, lp) __builtin_amdgcn_global_load_lds( \
    (const __attribute__((address_space(1))) void*)(gp), \
    (__attribute__((address_space(3))) void*)(lp), 16, 0, 0)

__device__ __forceinline__ u32 pkbf(float lo, float hi){
  u32 r;
  asm volatile("v_cvt_pk_bf16_f32 %0, %1, %2" : "=v"(r) : "v"(lo), "v"(hi));
  return r;
}

// ---------------------------------------------------------------- fused convert
__global__ __launch_bounds__(256) void cvt_all(
    const float* __restrict__ s0, const float* __restrict__ s1,
    const float* __restrict__ s2, const float* __restrict__ s3,
    const float* __restrict__ s4, const float* __restrict__ s5,
    const float* __restrict__ s6, u16* __restrict__ dst)
{
  const int i = (blockIdx.x * 256 + threadIdx.x) * 4;
  const float* sp;
  if      (i <  6291456) sp = s0 + i;
  else if (i <  6881280) sp = s1 + (i - 6291456);
  else if (i <  7471104) sp = s2 + (i - 6881280);
  else if (i <  8060928) sp = s3 + (i - 7471104);
  else if (i <  8650752) sp = s4 + (i - 8060928);
  else if (i < 11010048) sp = s5 + (i - 8650752);
  else                   sp = s6 + (i - 11010048);
  float4 f = *(const float4*)sp;
  u16x4 o = { f2b(f.x), f2b(f.y), f2b(f.z), f2b(f.w) };
  *(u16x4*)(dst + i) = o;
}

// ---------------------------------------------------------------- V transpose: packed qkv cols [1536,2304) -> vt[b,h,e,s]
// XOR-swizzled LDS tile: element (e,s) stored at t[e][s ^ 8*((e>>3)&3)] ->
// write conflicts 8-way -> 2-way (free); reads stay 16B-aligned vector loads.
__global__ __launch_bounds__(256) void transpose_v(const u16* __restrict__ qkv,
                                                   u16* __restrict__ vt){
  __shared__ short t[64][64];
  const int plane = blockIdx.y;                 // b*12 + h
  const int b = plane / 12, h = plane % 12;
  const u16* vp = qkv + (size_t)b * 2048 * 2304 + 1536 + h * 64;
  u16* vtp = vt + (size_t)plane * 2048 * 64;
  const int s0 = blockIdx.x * 64;
#pragma unroll
  for (int j = 0; j < 2; j++){
    int ch = threadIdx.x + 256*j;
    int r = ch >> 3, c = (ch & 7) << 3;       // r = s-row, c = e-chunk base
    short8 val = *(const short8*)(vp + (size_t)(s0 + r)*2304 + c);
    const int sw = r ^ (8 * ((c >> 3) & 3));  // e>>3 == c>>3 for jj<8
#pragma unroll
    for (int jj = 0; jj < 8; jj++) t[c + jj][sw] = val[jj];
  }
  __syncthreads();
#pragma unroll
  for (int j = 0; j < 2; j++){
    int ch = threadIdx.x + 256*j;
    int r = ch >> 3, c = (ch & 7) << 3;       // r = e-row, c = s-chunk
    const int sw = c ^ (8 * ((r >> 3) & 3));
    *(short8*)(vtp + (size_t)r*2048 + s0 + c) = *(const short8*)&t[r][sw];
  }
}

enum { EPI_QKV = 0, EPI_FFN1 = 2 };
__device__ __forceinline__ float KSCALE_C(){ return 0.125f * 1.44269504088896340736f; }

// ---------------------------------------------------------------- 128x128 2-phase GEMM, BK=32 (QKV / FFN1)
template<int EPI>
__global__ __launch_bounds__(256) void gemm_bt(
    const u16* __restrict__ A, const u16* __restrict__ Bm,
    int K, int gx, int ldc,
    u16* __restrict__ outB,
    const float* __restrict__ auxF)  // FFN1: b1
{
  __shared__ __align__(16) short Asm[128][32];
  __shared__ __align__(16) short Bsm[128][32];
  const int tid  = threadIdx.x;
  const int lane = tid & 63;
  const int wid  = tid >> 6;
  const int wr = wid >> 1, wc = wid & 1;
  const int fr = lane & 15, fq = lane >> 4;

  const int nwg = gridDim.x;
  const int lin = blockIdx.x;
  const int wg  = (lin & 7) * (nwg >> 3) + (lin >> 3);
  const int bx = wg % gx, by = wg / gx;
  const int m0 = by * 128, n0 = bx * 128;

  f32x4 acc[4][4];
#pragma unroll
  for (int i = 0; i < 4; i++)
#pragma unroll
    for (int j = 0; j < 4; j++) acc[i][j] = (f32x4){0.f, 0.f, 0.f, 0.f};

  const int lrow = lane >> 2;
  const int lcol = (lane & 3) << 3;

  for (int k0 = 0; k0 < K; k0 += 32) {
    const u16* ga = A  + (size_t)(m0 + wid*32 + lrow) * K + k0 + lcol;
    const u16* gb = Bm + (size_t)(n0 + wid*32 + lrow) * K + k0 + lcol;
    GLD16(ga,                 &Asm[wid*32][0]);
    GLD16(ga + (size_t)16*K,  &Asm[wid*32 + 16][0]);
    GLD16(gb,                 &Bsm[wid*32][0]);
    GLD16(gb + (size_t)16*K,  &Bsm[wid*32 + 16][0]);
    __syncthreads();

    short8 a[4], b[4];
#pragma unroll
    for (int i = 0; i < 4; i++) a[i] = *(const short8*)&Asm[wr*64 + i*16 + fr][fq*8];
#pragma unroll
    for (int j = 0; j < 4; j++) b[j] = *(const short8*)&Bsm[wc*64 + j*16 + fr][fq*8];
    __builtin_amdgcn_s_setprio(1);
#pragma unroll
    for (int i = 0; i < 4; i++)
#pragma unroll
      for (int j = 0; j < 4; j++)
        acc[i][j] = __builtin_amdgcn_mfma_f32_16x16x32_bf16(a[i], b[j], acc[i][j], 0, 0, 0);
    __builtin_amdgcn_s_setprio(0);
    __syncthreads();
  }

#pragma unroll
  for (int i = 0; i < 4; i++) {
    const int row0 = m0 + wr*64 + i*16 + fq*4;
#pragma unroll
    for (int j = 0; j < 4; j++) {
      const int col = n0 + wc*64 + j*16 + fr;
      const float ks = (EPI == EPI_QKV && col >= 768 && col < 1536) ? KSCALE_C() : 1.0f;
#pragma unroll
      for (int r = 0; r < 4; r++) {
        const int row = row0 + r;
        float val = acc[i][j][r];
        if (EPI == EPI_QKV) {
          outB[(size_t)row * ldc + col] = f2b(val * ks);
        } else { // EPI_FFN1
          float o = val + auxF[col];
          o = o > 0.f ? o : 0.f;
          outB[(size_t)row * ldc + col] = f2b(o);
        }
      }
    }
  }
}

// ---------------------------------------------------------------- 128x128 2-phase split-K GEMM (WO / FFN2)
__global__ __launch_bounds__(256) void gemm_split(
    const u16* __restrict__ A, const u16* __restrict__ Bm,
    int K, int KS, int gx,
    u16* __restrict__ outP)
{
  __shared__ __align__(16) short Asm[128][32];
  __shared__ __align__(16) short Bsm[128][32];
  const int tid  = threadIdx.x;
  const int lane = tid & 63;
  const int wid  = tid >> 6;
  const int wr = wid >> 1, wc = wid & 1;
  const int fr = lane & 15, fq = lane >> 4;

  const int nwg = gridDim.x;
  const int lin = blockIdx.x;
  const int wg  = (lin & 7) * (nwg >> 3) + (lin >> 3);
  const int per = gx * 64;               // blocks per K-slice
  const int ks  = wg / per;
  const int rem = wg % per;
  const int bx = rem % gx, by = rem / gx;
  const int m0 = by * 128, n0 = bx * 128;
  const int kbase = ks * KS;

  f32x4 acc[4][4];
#pragma unroll
  for (int i = 0; i < 4; i++)
#pragma unroll
    for (int j = 0; j < 4; j++) acc[i][j] = (f32x4){0.f, 0.f, 0.f, 0.f};

  const int lrow = lane >> 2;
  const int lcol = (lane & 3) << 3;

  for (int k0 = 0; k0 < KS; k0 += 32) {
    const u16* ga = A  + (size_t)(m0 + wid*32 + lrow) * K + kbase + k0 + lcol;
    const u16* gb = Bm + (size_t)(n0 + wid*32 + lrow) * K + kbase + k0 + lcol;
    GLD16(ga,                 &Asm[wid*32][0]);
    GLD16(ga + (size_t)16*K,  &Asm[wid*32 + 16][0]);
    GLD16(gb,                 &Bsm[wid*32][0]);
    GLD16(gb + (size_t)16*K,  &Bsm[wid*32 + 16][0]);
    __syncthreads();

    short8 a[4], b[4];
#pragma unroll
    for (int i = 0; i < 4; i++) a[i] = *(const short8*)&Asm[wr*64 + i*16 + fr][fq*8];
#pragma unroll
    for (int j = 0; j < 4; j++) b[j] = *(const short8*)&Bsm[wc*64 + j*16 + fr][fq*8];
    __builtin_amdgcn_s_setprio(1);
#pragma unroll
    for (int i = 0; i < 4; i++)
#pragma unroll
      for (int j = 0; j < 4; j++)
        acc[i][j] = __builtin_amdgcn_mfma_f32_16x16x32_bf16(a[i], b[j], acc[i][j], 0, 0, 0);
    __builtin_amdgcn_s_setprio(0);
    __syncthreads();
  }

  u16* op = outP + (size_t)ks * 6291456;   // 8192*768
#pragma unroll
  for (int i = 0; i < 4; i++) {
    const int row0 = m0 + wr*64 + i*16 + fq*4;
#pragma unroll
    for (int j = 0; j < 4; j++) {
      const int col = n0 + wc*64 + j*16 + fr;
#pragma unroll
      for (int r = 0; r < 4; r++)
        op[(size_t)(row0 + r) * 768 + col] = f2b(acc[i][j][r]);
    }
  }
}

// ---------------------------------------------------------------- flash attention: 8 waves, QBLK=128 (packed-qkv)
__global__ __launch_bounds__(512) void flash_attn(
    const u16* __restrict__ qkv, const u16* __restrict__ vtmat,
    u16* __restrict__ ctx)
{
  const int tid = threadIdx.x;
  const int lane = tid & 63, wid = tid >> 6;       // wid 0..7
  const int fr = lane & 15, fq = lane >> 4;
  const int orig = blockIdx.x;
  const int wg = (orig & 7) * 96 + (orig >> 3);    // bijective XCD swizzle (768=8*96)
  const int qb = wg & 15;
  const int ph = wg >> 4;
  const int b = ph / 12, h = ph % 12;
  const u16* qp  = qkv + (size_t)b * 2048 * 2304 + h * 64;          // q cols [0,768)
  const u16* kp  = qkv + (size_t)b * 2048 * 2304 + 768 + h * 64;    // k cols [768,1536)
  const u16* vtp = vtmat + (size_t)ph * 2048 * 64;

  __shared__ __align__(16) short Ksm[2][64][64];
  __shared__ __align__(16) short Vsm[2][64][64];

  const int qr0 = qb*128 + wid*16;
  const short8 aq0 = *(const short8*)(qp + (size_t)(qr0 + fr)*2304 + fq*8);
  const short8 aq1 = *(const short8*)(qp + (size_t)(qr0 + fr)*2304 + 32 + fq*8);

  short8 vones;
#pragma unroll
  for (int j = 0; j < 8; j++) vones[j] = (short)0x3F80;   // bf16 1.0

  const int rA = wid*8 + (lane >> 3);
  const int cA = (((lane & 7) ^ ((rA & 3) | (((rA >> 3) & 1) << 2)))) * 8;

#define STAGE(B, KT) do { \
    GLD16(kp  + (size_t)((KT)*64 + rA)*2304 + cA,  &Ksm[B][wid*8][0]); \
    GLD16(vtp + (size_t)rA*2048 + (KT)*64 + cA,    &Vsm[B][wid*8][0]); \
  } while(0)

  f32x4 o[4];
#pragma unroll
  for (int eb = 0; eb < 4; eb++) o[eb] = (f32x4){0.f, 0.f, 0.f, 0.f};
  float m = -1e30f, l = 0.f;
  const f32x4 zero = (f32x4){0.f, 0.f, 0.f, 0.f};

  STAGE(0, 0);
  __syncthreads();

  const int fK  = (fr & 3) | (((fr >> 2) & 1) << 2);
  const int kc0 = ((fq    ) ^ fK) * 8;
  const int kc1 = ((4 + fq) ^ fK) * 8;
  const int krow = (fr & 3) + 8 * (fr >> 2);
  const int fV  = (fr & 3) | (((fr >> 3) & 1) << 2);
  const int vc0 = ((fq    ) ^ fV) * 8;
  const int vc1 = ((4 + fq) ^ fV) * 8;

  int buf = 0;
  for (int kt = 0; kt < 32; ++kt) {
    if (kt < 31) STAGE(buf ^ 1, kt + 1);

    f32x4 st[2][2];
    __builtin_amdgcn_s_setprio(1);
#pragma unroll
    for (int h2 = 0; h2 < 2; h2++)
#pragma unroll
      for (int c = 0; c < 2; c++) {
        const short* kr = &Ksm[buf][32*h2 + 4*c + krow][0];
        short8 kf0 = *(const short8*)(kr + kc0);
        short8 kf1 = *(const short8*)(kr + kc1);
        f32x4 a = __builtin_amdgcn_mfma_f32_16x16x32_bf16(kf0, aq0, zero, 0, 0, 0);
        st[h2][c] = __builtin_amdgcn_mfma_f32_16x16x32_bf16(kf1, aq1, a,    0, 0, 0);
      }
    __builtin_amdgcn_s_setprio(0);

    float t0 = fmaxf(fmaxf(st[0][0][0], st[0][0][1]), st[0][0][2]);
    float t1 = fmaxf(fmaxf(st[0][0][3], st[0][1][0]), st[0][1][1]);
    float t2 = fmaxf(fmaxf(st[0][1][2], st[0][1][3]), st[1][0][0]);
    float t3 = fmaxf(fmaxf(st[1][0][1], st[1][0][2]), st[1][0][3]);
    float t4 = fmaxf(fmaxf(st[1][1][0], st[1][1][1]), st[1][1][2]);
    float u0 = fmaxf(fmaxf(t0, t1), st[1][1][3]);
    float u1 = fmaxf(fmaxf(t2, t3), t4);
    float lm = fmaxf(u0, u1);
    lm = fmaxf(lm, __shfl_xor(lm, 16));
    lm = fmaxf(lm, __shfl_xor(lm, 32));

    if (!__all(lm <= m + 8.f)) {
      float nm = fmaxf(m, lm);
      float corr = EXP2(m - nm);
      m = nm;
      l *= corr;
#pragma unroll
      for (int eb = 0; eb < 4; eb++)
#pragma unroll
        for (int r = 0; r < 4; r++) o[eb][r] *= corr;
    }

    float p[2][2][4];
#pragma unroll
    for (int h2 = 0; h2 < 2; h2++)
#pragma unroll
      for (int c = 0; c < 2; c++)
#pragma unroll
        for (int r = 0; r < 4; r++)
          p[h2][c][r] = EXP2(st[h2][c][r] - m);

    union { u32 u[4]; short8 s8; } pf0, pf1;
    pf0.u[0] = pkbf(p[0][0][0], p[0][0][1]);
    pf0.u[1] = pkbf(p[0][0][2], p[0][0][3]);
    pf0.u[2] = pkbf(p[0][1][0], p[0][1][1]);
    pf0.u[3] = pkbf(p[0][1][2], p[0][1][3]);
    pf1.u[0] = pkbf(p[1][0][0], p[1][0][1]);
    pf1.u[1] = pkbf(p[1][0][2], p[1][0][3]);
    pf1.u[2] = pkbf(p[1][1][0], p[1][1][1]);
    pf1.u[3] = pkbf(p[1][1][2], p[1][1][3]);

    __builtin_amdgcn_s_setprio(1);
    f32x4 ol = __builtin_amdgcn_mfma_f32_16x16x32_bf16(vones, pf0.s8, zero, 0, 0, 0);
    ol       = __builtin_amdgcn_mfma_f32_16x16x32_bf16(vones, pf1.s8, ol,   0, 0, 0);
#pragma unroll
    for (int eb = 0; eb < 4; eb++) {
      const short* vr = &Vsm[buf][eb*16 + fr][0];
      o[eb] = __builtin_amdgcn_mfma_f32_16x16x32_bf16(*(const short8*)(vr + vc0), pf0.s8, o[eb], 0, 0, 0);
      o[eb] = __builtin_amdgcn_mfma_f32_16x16x32_bf16(*(const short8*)(vr + vc1), pf1.s8, o[eb], 0, 0, 0);
    }
    __builtin_amdgcn_s_setprio(0);
    l += ol[0];

    __syncthreads();
    buf ^= 1;
  }
#undef STAGE

  const float inv = 1.0f / l;
  const int s = qr0 + fr;
  u16* cp = ctx + ((size_t)(b*2048 + s)) * 768 + h*64;
#pragma unroll
  for (int eb = 0; eb < 4; eb++) {
    u16x4 w = { f2b(o[eb][0]*inv), f2b(o[eb][1]*inv), f2b(o[eb][2]*inv), f2b(o[eb][3]*inv) };
    *(u16x4*)(cp + eb*16 + fq*4) = w;
  }
}

// ---------------------------------------------------------------- layernorm over p0+p1+extra(+bias)
template<int HASBIAS, int F32OUT>
__global__ __launch_bounds__(256) void ln_add_k(
    const u16* __restrict__ p0, const u16* __restrict__ p1, const u16* __restrict__ extra,
    const float* __restrict__ bias,
    const float* __restrict__ g, const float* __restrict__ be, void* __restrict__ outp)
{
  const int lane = threadIdx.x & 63, wid = threadIdx.x >> 6;
  const int row = blockIdx.x * 4 + wid;
  const size_t base = (size_t)row * 768;
  float v[12];
  float s = 0.f, s2 = 0.f;
#pragma unroll
  for (int i = 0; i < 6; i++) {
    int c = i*128 + lane*2;
    ushort2 a0 = *(const ushort2*)(p0 + base + c);
    ushort2 a1 = *(const ushort2*)(p1 + base + c);
    ushort2 ax = *(const ushort2*)(extra + base + c);
    float v0 = b2f(a0.x) + b2f(a1.x) + b2f(ax.x);
    float v1 = b2f(a0.y) + b2f(a1.y) + b2f(ax.y);
    if (HASBIAS) { v0 += bias[c]; v1 += bias[c+1]; }
    v[2*i] = v0; v[2*i+1] = v1;
    s += v0 + v1;
    s2 += v0*v0 + v1*v1;
  }
#pragma unroll
  for (int msk = 1; msk < 64; msk <<= 1) { s += __shfl_xor(s, msk); s2 += __shfl_xor(s2, msk); }
  const float mu = s * (1.f/768.f);
  const float var = s2 * (1.f/768.f) - mu*mu;
  const float rstd = rsqrtf(var + 1e-5f);
#pragma unroll
  for (int i = 0; i < 6; i++) {
    int c = i*128 + lane*2;
    float o0 = (v[2*i]   - mu) * rstd * g[c]   + be[c];
    float o1 = (v[2*i+1] - mu) * rstd * g[c+1] + be[c+1];
    if (F32OUT) {
      float2 w = { o0, o1 };
      *(float2*)((float*)outp + base + c) = w;
    } else {
      ushort2 w = { f2b(o0), f2b(o1) };
      *(ushort2*)((u16*)outp + base + c) = w;
    }
  }
}

// ---------------------------------------------------------------- launch
extern "C" void kernel_launch(void* const* d_in, const int* in_sizes, int n_in,
                              void* d_out, int out_size, void* d_ws, size_t ws_size,
                              hipStream_t stream)
{
  const float* x   = (const float*)d_in[0];
  const float* Wq  = (const float*)d_in[1];
  const float* Wk  = (const float*)d_in[2];
  const float* Wv  = (const float*)d_in[3];
  const float* Wo  = (const float*)d_in[4];
  const float* W1  = (const float*)d_in[5];
  const float* b1  = (const float*)d_in[6];
  const float* W2  = (const float*)d_in[7];
  const float* b2  = (const float*)d_in[8];
  const float* g1  = (const float*)d_in[9];
  const float* be1 = (const float*)d_in[10];
  const float* g2  = (const float*)d_in[11];
  const float* be2 = (const float*)d_in[12];
  float* out = (float*)d_out;

  char* ws = (char*)d_ws;
  u16* xb     = (u16*)(ws + 0);
  u16* Wqkv_b = (u16*)(ws + 12582912);
  u16* Wo_b   = (u16*)(ws + 16121856);
  u16* W1_b   = (u16*)(ws + 17301504);
  u16* W2_b   = (u16*)(ws + 22020096);
  u16* qkv    = (u16*)(ws + 26738688);     // packed [8192][2304]
  u16* ctxb   = (u16*)(ws + 64487424);
  u16* hidden = (u16*)(ws + 26738688);     // alias qkv+ctx
  u16* vt     = (u16*)(ws + 77070336);     // V^T [b,h,e,s] (dead after flash)
  u16* part   = (u16*)(ws + 77070336);     // split-K partials [2][8192][768] bf16 (alias vt)
  u16* hb     = (u16*)(ws + 102236160);

  cvt_all<<<dim3(13056), 256, 0, stream>>>(x, Wq, Wk, Wv, Wo, W1, W2, (u16*)ws);

  // QKV: [8192,768] @ [2304,768]^T -> packed [8192,2304] (grid 18*64=1152)
  gemm_bt<EPI_QKV><<<dim3(1152), 256, 0, stream>>>(
      xb, Wqkv_b, 768, 18, 2304, qkv, nullptr);

  transpose_v<<<dim3(32, 48), 256, 0, stream>>>(qkv, vt);

  // flash: 8 waves/block, QBLK=128 (grid 768 = 3.0/CU)
  flash_attn<<<dim3(768), 512, 0, stream>>>(qkv, vt, ctxb);

  u16* p0 = part;
  u16* p1 = part + 6291456;

  // WO split-K=2: [8192,768] @ [768,768]^T -> partials (grid 768 = 3.0/CU, 12 iters/block)
  gemm_split<<<dim3(768), 256, 0, stream>>>(ctxb, Wo_b, 768, 384, 6, part);

  // LN1: LN(p0 + p1 + x) -> hb
  ln_add_k<0, 0><<<2048, 256, 0, stream>>>(p0, p1, xb, nullptr, g1, be1, hb);

  // FFN1: [8192,768] @ [3072,768]^T  (grid 24*64=1536)
  gemm_bt<EPI_FFN1><<<dim3(1536), 256, 0, stream>>>(
      hb, W1_b, 768, 24, 3072, hidden, b1);

  // FFN2 split-K=2: [8192,3072] @ [768,3072]^T -> partials (grid 768, 48 iters/block)
  gemm_split<<<dim3(768), 256, 0, stream>>>(hidden, W2_b, 3072, 1536, 6, part);

  // LN2: LN(p0 + p1 + hb + b2) -> out (f32)
  ln_add_k<1, 1><<<2048, 256, 0, stream>>>(p0, p1, hb, b2, g2, be2, out);
}